// Round 6
// baseline (511.173 us; speedup 1.0000x reference)
//
#include <hip/hip_runtime.h>
#include <hip/hip_bf16.h>
#include <hip/hip_fp16.h>

// GAE: 8 stacked GAT layers on N=4096 nodes, dims 512->256->128->64->16->64->128->256->512.
// Outputs (concat in d_out): x_bar[4096*512], h1[4096*256], h2[4096*128], h3[4096*64], h4[4096*16].
//
// Per layer:
//   H = X @ W                      (bf16 MFMA GEMM, fp32 accum; HTt fp16 j-tiled layout written
//                                   directly from the GEMM epilogue via LDS)
//   src = H @ a[:f], tgt = H @ a[f:]; Ev16 = half(exp(t-TM)*2^14), Gv16 = half(exp(.2(t-TM))*2^4)
//     with CONSTANT TM=12 (factorization exact for any upper bound TM >= max tgt)
//   pass2f: OUT[i,:] = softmax_j(lrelu(s_i+t_j) masked) @ H computed UNNORMALIZED + ones-column:
//     w~_ij = max(P_i*Ev_j, Q_i*Gv_j) in packed fp16 (P,Q from src_i in-kernel — NO pass1 kernel);
//     lsum_i = sum_j w~_ij accumulated by an extra MFMA with B = all-ones. js==1: divide in
//     epilogue; js>1: lsum partials (ls0/part_ls) folded + divided in reduce_add.
//
// Round-6: R0 configs (proven 461us: F=512 NF8/js1, 256 NF8/js2, 128 NF8/js4, 64 NF4/js4,
// 16 NF1/js4) + inner-loop rework. Evidence: residency reg-capped at ~2 blk/CU (108 VGPR +
// ~72 acc); grid scaling (R4/R5) no help; fc scaling linear in A-build VALU (R5: fc 4->8 =
// +20us); both pipes <30% busy -> ~25us/dispatch is LOAD-LATENCY STALL. Fix: flat j-loop with
// DEPTH-1 REGISTER PREFETCH (ping-pong A/B sets: bfr + Ev/Gv + adjacency) so each wave keeps
// next iteration's ~8.5KB in flight under current iteration's VALU+MFMA (~500cyc cover).
// Also: sign-extend bit masks ((bb<<k)>>31) replace cndmask chains (bit-exact), pointers
// strength-reduced. Per-row j-accumulation order unchanged -> bitwise-identical outputs.
// NO atomics, no memset -> bitwise deterministic.

#define NROWS 4096
#define TMC 12.0f

typedef __attribute__((ext_vector_type(8))) short v8s;
typedef __attribute__((ext_vector_type(8))) _Float16 v8h;
typedef __attribute__((ext_vector_type(2))) _Float16 h2v;
typedef __attribute__((ext_vector_type(4))) float v4f;

__device__ inline unsigned short f2bf(float x) {
  union { float f; unsigned u; } v; v.f = x;
  unsigned r = v.u + 0x7fffu + ((v.u >> 16) & 1u);   // RNE
  return (unsigned short)(r >> 16);
}

// ---- pack adj (int32 0/1) -> bitmask, 64 uint64 words per row ----
__global__ void pack_adj(const int* __restrict__ adj, unsigned long long* __restrict__ bits) {
  int row = blockIdx.x;
  int lane = threadIdx.x & 63, wave = threadIdx.x >> 6;
  for (int w = wave; w < 64; w += 4) {
    unsigned long long m = __ballot(adj[(size_t)row * NROWS + w * 64 + lane] > 0);
    if (lane == 0) bits[row * 64 + w] = m;
  }
}

// ---- batched W transpose: fp32 [K][F] -> bf16 [F][K], all 8 layers in one launch ----
struct WTArgs { const float* src[8]; unsigned short* dst[8]; int K[8]; int F[8]; };
__global__ void transpose_w(WTArgs A) {
  int z = blockIdx.z;
  const float* in = A.src[z];
  unsigned short* out = A.dst[z];
  int R = A.K[z], C = A.F[z];
  __shared__ unsigned short tile[32][33];
  int c0 = blockIdx.x * 32, r0 = blockIdx.y * 32;
  if (c0 >= C || r0 >= R) return;          // block-uniform: safe before barrier
#pragma unroll
  for (int dy = 0; dy < 32; dy += 8) {
    int r = r0 + threadIdx.y + dy, c = c0 + threadIdx.x;
    if (r < R && c < C) tile[threadIdx.y + dy][threadIdx.x] = f2bf(in[(size_t)r * C + c]);
  }
  __syncthreads();
#pragma unroll
  for (int dy = 0; dy < 32; dy += 8) {
    int c = c0 + threadIdx.y + dy, r = r0 + threadIdx.x;
    if (r < R && c < C) out[(size_t)c * R + r] = tile[threadIdx.x][threadIdx.y + dy];
  }
}

// ---- C[4096][Nf] = A_f32[4096][K] x B[K][Nf], B given as BT[Nf][K] bf16 ----
// 2 waves/block, 16 rows each; grid (128, ceil(Nf/64)).
// Epilogue writes HTt[j/32][f][j%32] in fp16 directly (LDS-staged).
__global__ __launch_bounds__(128) void gemm_xw(const float* __restrict__ A,
                                               const unsigned short* __restrict__ BT,
                                               float* __restrict__ C,
                                               unsigned short* __restrict__ HTt,
                                               int K, int Nf) {
  __shared__ unsigned short zone[64 * 36];         // [f_local][j_local], stride 36 vs banks
  int lane = threadIdx.x & 63, wave = threadIdx.x >> 6;
  int quad = lane >> 4, l16 = lane & 15;
  int row0 = blockIdx.x * 32 + wave * 16;
  int col0 = blockIdx.y * 64;
  int nf = Nf - col0; nf = nf > 64 ? 4 : (nf + 15) / 16;
  v4f acc[4] = {{0.f,0.f,0.f,0.f},{0.f,0.f,0.f,0.f},{0.f,0.f,0.f,0.f},{0.f,0.f,0.f,0.f}};
  for (int k0 = 0; k0 < K; k0 += 32) {
    int kk = k0 + quad * 8;
    v8s a = {0,0,0,0,0,0,0,0};
    if (kk < K) {
      float4 f0 = *(const float4*)(A + (size_t)(row0 + l16) * K + kk);
      float4 f1 = *(const float4*)(A + (size_t)(row0 + l16) * K + kk + 4);
      union { v8s s; __hip_bfloat162 h[4]; } ua;
      ua.h[0] = __float22bfloat162_rn(make_float2(f0.x, f0.y));
      ua.h[1] = __float22bfloat162_rn(make_float2(f0.z, f0.w));
      ua.h[2] = __float22bfloat162_rn(make_float2(f1.x, f1.y));
      ua.h[3] = __float22bfloat162_rn(make_float2(f1.z, f1.w));
      a = ua.s;
    }
    for (int t = 0; t < nf; t++) {
      v8s b = {0,0,0,0,0,0,0,0};
      if (kk < K) b = *(const v8s*)(BT + (size_t)(col0 + t * 16 + l16) * K + kk);
      acc[t] = __builtin_amdgcn_mfma_f32_16x16x32_bf16(a, b, acc[t], 0, 0, 0);
    }
  }
  for (int t = 0; t < nf; t++) {
#pragma unroll
    for (int r = 0; r < 4; r++) {
      float v = acc[t][r];
      C[(size_t)(row0 + quad * 4 + r) * Nf + col0 + t * 16 + l16] = v;
      union { _Float16 h; unsigned short s; } cv; cv.h = (_Float16)v;
      zone[(t * 16 + l16) * 36 + wave * 16 + quad * 4 + r] = cv.s;
    }
  }
  __syncthreads();
  unsigned* dst = (unsigned*)(HTt + (size_t)(blockIdx.x) * Nf * 32 + (size_t)col0 * 32);
  const unsigned* zsrc = (const unsigned*)zone;
  int total = nf * 256;                            // dwords (nf*16 f-rows x 32 shorts each)
  for (int idx = threadIdx.x; idx < total; idx += 128) {
    int f = idx >> 4, jp = idx & 15;
    dst[idx] = zsrc[f * 18 + jp];
  }
}

// ---- src + scaled-fp16 Ev/Gv: per-row dots of H with a[:f], a[f:] ----
__global__ void gemv_srctgt(const float* __restrict__ H, const float* __restrict__ a,
                            float* __restrict__ src, unsigned short* __restrict__ Ev16,
                            unsigned short* __restrict__ Gv16, int f) {
  int row = blockIdx.x * 4 + (threadIdx.x >> 6);
  int lane = threadIdx.x & 63;
  float s = 0.f, t = 0.f;
  for (int k = lane; k < f; k += 64) {
    float h = H[(size_t)row * f + k];
    s += h * a[k];
    t += h * a[f + k];
  }
#pragma unroll
  for (int off = 32; off; off >>= 1) { s += __shfl_down(s, off); t += __shfl_down(t, off); }
  if (lane == 0) {
    src[row] = s;
    union { _Float16 h; unsigned short u; } ce, cg;
    ce.h = (_Float16)(__expf(t - TMC) * 16384.f);  // *2^14 (exact pow2)
    cg.h = (_Float16)(__expf(0.2f * (t - TMC)) * 16.f);   // *2^4 (exact pow2)
    Ev16[row] = ce.u;
    Gv16[row] = cg.u;
  }
}

// ---- pass2f: OUT = P @ H unnormalized + MFMA ones-column lsum; packed fp16 A-build ----
// 32-row i-tile (NI=2); grid (128, fc, js). Flat j-loop with depth-1 register prefetch.
template<int NF>
__global__ __launch_bounds__(256) void pass2f(const unsigned* __restrict__ adjW,
                                              const float* __restrict__ src,
                                              const unsigned short* __restrict__ Ev16,
                                              const unsigned short* __restrict__ Gv16,
                                              const unsigned short* __restrict__ HTt,
                                              float* __restrict__ out,
                                              float* __restrict__ part,
                                              float* __restrict__ ls0,
                                              float* __restrict__ part_ls, int F, int js) {
  const int W = NF * 16, Wp = W + 4;               // pad col W holds lsum; rest kills conflicts
  __shared__ float zone[32 * Wp];
  int lane = threadIdx.x & 63, wave = threadIdx.x >> 6;
  int quad = lane >> 4, l16 = lane & 15;
  int i0 = blockIdx.x * 32;
  int fc0 = blockIdx.y * W;
  const size_t F32 = (size_t)F * 32;
  int jrange = NROWS / js;
  int jlen = jrange / 4;                           // multiple of 128 for js in {1,2,4}
  int jstart = blockIdx.z * jrange + wave * jlen;

  h2v Ai2[2], Bi2[2];
  const unsigned* arow[2];
#pragma unroll
  for (int ni = 0; ni < 2; ni++) {
    int i = i0 + ni * 16 + l16;
    float sp = src[i] + TMC;                       // s' = s + TM
    float m = sp > 0.f ? sp : 0.2f * sp;           // lrelu(s') >= lrelu(s+t_j) since t_j <= TM
    _Float16 ai = (_Float16)(__expf(sp - m) * 0x1p-14f);       // Ai'*Ev16 = exp(e-m) exactly
    _Float16 bi = (_Float16)(__expf(0.2f * sp - m) * 0x1p-4f); // Bi'*Gv16 = exp(.2e-m) exactly
    Ai2[ni] = (h2v){ai, ai};
    Bi2[ni] = (h2v){bi, bi};
    arow[ni] = adjW + (size_t)i * 128;             // 128 adjacency dwords per row
  }
  const v8h ones = {(_Float16)1.f, (_Float16)1.f, (_Float16)1.f, (_Float16)1.f,
                    (_Float16)1.f, (_Float16)1.f, (_Float16)1.f, (_Float16)1.f};
  v4f acc[2][NF], accl[2];
#pragma unroll
  for (int ni = 0; ni < 2; ni++) {
    accl[ni] = (v4f){0.f, 0.f, 0.f, 0.f};
#pragma unroll
    for (int t = 0; t < NF; t++) acc[ni][t] = (v4f){0.f, 0.f, 0.f, 0.f};
  }

  // ---- flat j-loop with depth-1 register prefetch (ping-pong A/B) ----
  union bun { v8s s; v8h h; };
  const unsigned short* bpw =
      HTt + ((size_t)(jstart >> 5)) * F32 + (size_t)(fc0 + l16) * 32 + quad * 8;
  const unsigned short* evp = Ev16 + jstart + quad * 8;
  const unsigned short* gvp = Gv16 + jstart + quad * 8;
  int awi = jstart >> 5;
  int nIt = jlen >> 5;                             // even for all configs (>= 8)

  bun bfA[NF], bfB[NF];
  v8s ueA, ugA, ueB, ugB;
  unsigned awA[2], awB[2];

  // prologue: set A = iteration 0
#pragma unroll
  for (int t = 0; t < NF; t++) bfA[t].s = *(const v8s*)(bpw + t * 512);
  ueA = *(const v8s*)evp; ugA = *(const v8s*)gvp;
  awA[0] = arow[0][awi]; awA[1] = arow[1][awi];

  auto compute = [&](const bun (&bf)[NF], v8s ues, v8s ugs, const unsigned (&aww)[2]) {
    union { v8s s; h2v h2[4]; } ue, ug;
    ue.s = ues; ug.s = ugs;
#pragma unroll
    for (int ni = 0; ni < 2; ni++) {
      unsigned bb = aww[ni] >> (quad * 8);
      union { v8h h; unsigned u32[4]; } ua;
#pragma unroll
      for (int p = 0; p < 4; p++) {
        h2v w2 = __builtin_elementwise_max(Ai2[ni] * ue.h2[p], Bi2[ni] * ug.h2[p]);
        // sign-extend bit (2p) / (2p+1) -> 0 or 0xFFFFFFFF (bit-exact vs cndmask form)
        unsigned lo = (unsigned)((int)(bb << (31 - 2 * p)) >> 31);
        unsigned hi = (unsigned)((int)(bb << (30 - 2 * p)) >> 31);
        union { h2v h2; unsigned u; } tw; tw.h2 = w2;
        ua.u32[p] = tw.u & ((lo & 0x0000FFFFu) | (hi & 0xFFFF0000u));
      }
#pragma unroll
      for (int t = 0; t < NF; t++)
        acc[ni][t] = __builtin_amdgcn_mfma_f32_16x16x32_f16(ua.h, bf[t].h, acc[ni][t], 0, 0, 0);
      accl[ni] = __builtin_amdgcn_mfma_f32_16x16x32_f16(ua.h, ones, accl[ni], 0, 0, 0);
    }
  };

  for (int it = 0; it < nIt; it += 2) {
    // prefetch B = iteration it+1 (always valid: nIt even)
    {
      const unsigned short* bp1 = bpw + F32;
#pragma unroll
      for (int t = 0; t < NF; t++) bfB[t].s = *(const v8s*)(bp1 + t * 512);
      ueB = *(const v8s*)(evp + 32); ugB = *(const v8s*)(gvp + 32);
      awB[0] = arow[0][awi + 1]; awB[1] = arow[1][awi + 1];
    }
    compute(bfA, ueA, ugA, awA);
    // prefetch A = iteration it+2 (clamped reload of current on the final pair; discarded)
    {
      size_t adv = (it + 2 < nIt) ? 2 : 0;
      const unsigned short* bp2 = bpw + adv * F32;
      const unsigned short* ev2 = evp + adv * 32;
      const unsigned short* gv2 = gvp + adv * 32;
      int aw2 = awi + (int)adv;
#pragma unroll
      for (int t = 0; t < NF; t++) bfA[t].s = *(const v8s*)(bp2 + t * 512);
      ueA = *(const v8s*)ev2; ugA = *(const v8s*)gv2;
      awA[0] = arow[0][aw2]; awA[1] = arow[1][aw2];
    }
    compute(bfB, ueB, ugB, awB);
    bpw += 2 * F32; evp += 64; gvp += 64; awi += 2;
  }

  // deterministic combine: waves add into zone in fixed order (lsum in column W)
  for (int w = 0; w < 4; w++) {
    if (wave == w) {
#pragma unroll
      for (int ni = 0; ni < 2; ni++) {
#pragma unroll
        for (int t = 0; t < NF; t++)
#pragma unroll
          for (int r = 0; r < 4; r++) {
            int idx = (ni * 16 + quad * 4 + r) * Wp + t * 16 + l16;
            if (w == 0) zone[idx] = acc[ni][t][r];
            else        zone[idx] += acc[ni][t][r];
          }
        if (l16 == 0) {
#pragma unroll
          for (int r = 0; r < 4; r++) {
            int idx = (ni * 16 + quad * 4 + r) * Wp + W;
            if (w == 0) zone[idx] = accl[ni][r];
            else        zone[idx] += accl[ni][r];
          }
        }
      }
    }
    __syncthreads();
  }

  if (js == 1) {
    if (threadIdx.x < 32) zone[threadIdx.x * Wp + W] = 1.0f / zone[threadIdx.x * Wp + W];
    __syncthreads();
    for (int idx = threadIdx.x; idx < 32 * W; idx += 256) {
      int rrow = idx / W, ccol = idx - rrow * W;
      out[(size_t)(i0 + rrow) * F + fc0 + ccol] = zone[rrow * Wp + ccol] * zone[rrow * Wp + W];
    }
  } else {
    float* dst = (blockIdx.z == 0) ? out : part + (size_t)(blockIdx.z - 1) * NROWS * F;
    for (int idx = threadIdx.x; idx < 32 * W; idx += 256) {
      int rrow = idx / W, ccol = idx - rrow * W;
      dst[(size_t)(i0 + rrow) * F + fc0 + ccol] = zone[rrow * Wp + ccol];
    }
    if (threadIdx.x < 32) {
      float l = zone[threadIdx.x * Wp + W];
      if (blockIdx.z == 0) ls0[i0 + threadIdx.x] = l;             // fc dups write same value
      else part_ls[(size_t)(blockIdx.z - 1) * NROWS + i0 + threadIdx.x] = l;
    }
  }
}

// ---- deterministic cross-z fold + normalize: out = (out + sum slabs) / (ls0 + sum part_ls) ----
__global__ void reduce_add(const float* __restrict__ part, const float* __restrict__ part_ls,
                           const float* __restrict__ ls0, float* __restrict__ out, int n, int F,
                           int nslab) {
  int i = blockIdx.x * 256 + threadIdx.x;
  if (i < n) {
    int row = i / F;                               // F is a power of two
    float s = out[i];
    float l = ls0[row];
    for (int z = 0; z < nslab; z++) s += part[(size_t)z * n + i];
    for (int z = 0; z < nslab; z++) l += part_ls[(size_t)z * NROWS + row];
    out[i] = s / l;
  }
}

static void launch_pass2(int NF, dim3 grid, const unsigned* adjW, const float* src,
                         const unsigned short* Ev16, const unsigned short* Gv16,
                         const unsigned short* HTt, float* out, float* part, float* ls0,
                         float* part_ls, int F, int js, hipStream_t stream) {
  switch (NF) {
    case 8: pass2f<8><<<grid, 256, 0, stream>>>(adjW, src, Ev16, Gv16, HTt, out, part, ls0,
                                                part_ls, F, js); break;
    case 4: pass2f<4><<<grid, 256, 0, stream>>>(adjW, src, Ev16, Gv16, HTt, out, part, ls0,
                                                part_ls, F, js); break;
    default: pass2f<1><<<grid, 256, 0, stream>>>(adjW, src, Ev16, Gv16, HTt, out, part, ls0,
                                                 part_ls, F, js); break;
  }
}

extern "C" void kernel_launch(void* const* d_in, const int* in_sizes, int n_in,
                              void* d_out, int out_size, void* d_ws, size_t ws_size,
                              hipStream_t stream) {
  static const int fin[8]  = {512, 256, 128, 64, 16, 64, 128, 256};
  static const int fout[8] = {256, 128, 64, 16, 64, 128, 256, 512};

  const float* x = (const float*)d_in[0];
  const int* adj = (const int*)d_in[1];
  char* ws = (char*)d_ws;
  unsigned long long* bits = (unsigned long long*)(ws);                 // 2 MB
  unsigned short* WTall = (unsigned short*)(ws + (2u << 20));           // <1 MB, all layers
  float* H            = (float*)(ws + (6u << 20));                      // 8 MB max
  unsigned short* HTt = (unsigned short*)(ws + (14u << 20));            // 4 MB max (fp16)
  float* srcv    = (float*)(ws + (19u << 20));                          // 16 KB
  float* ls0     = (float*)(ws + (19u << 20) + (16u << 10));            // 16 KB
  float* part_ls = (float*)(ws + (19u << 20) + (32u << 10));            // 112 KB (7 slabs)
  unsigned short* Ev16 = (unsigned short*)(ws + (19u << 20) + (160u << 10));  // 8 KB
  unsigned short* Gv16 = (unsigned short*)(ws + (19u << 20) + (168u << 10));  // 8 KB
  float* o5    = (float*)(ws + (20u << 20));                            // 1 MB
  float* o6    = (float*)(ws + (21u << 20));                            // 2 MB
  float* o7    = (float*)(ws + (23u << 20));                            // 4 MB
  // partial slabs ((js-1)*N*F*4 <= 8MB) alias H: H's last reader (gemv_srctgt) runs
  // before pass2f; next layer's gemm_xw rewrites H afterwards (stream-ordered).
  float* part = H;

  float* outp = (float*)d_out;
  float* xbar = outp;
  float* h1 = outp + (size_t)NROWS * 512;
  float* h2 = h1 + (size_t)NROWS * 256;
  float* h3 = h2 + (size_t)NROWS * 128;
  float* h4 = h3 + (size_t)NROWS * 64;

  float* louts[8] = {h1, h2, h3, h4, o5, o6, o7, xbar};
  const float* lins[8] = {x, h1, h2, h3, h4, o5, o6, o7};

  unsigned short* WT[8];
  { size_t off = 0;
    for (int t = 0; t < 8; t++) { WT[t] = WTall + off; off += (size_t)fin[t] * fout[t]; } }

  pack_adj<<<dim3(4096), dim3(256), 0, stream>>>(adj, bits);

  WTArgs wa;
  for (int t = 0; t < 8; t++) {
    wa.src[t] = (const float*)d_in[2 + 2 * t];
    wa.dst[t] = WT[t];
    wa.K[t] = fin[t];
    wa.F[t] = fout[t];
  }
  transpose_w<<<dim3(16, 16, 8), dim3(32, 8), 0, stream>>>(wa);

  for (int t = 0; t < 8; t++) {
    int K = fin[t], F = fout[t];
    const float* At = (const float*)d_in[3 + 2 * t];
    const float* Xin = lins[t];
    float* Ot = louts[t];

    // R0's proven configs: minimize fc (A-build replicas) at NF=8; 512-block grids.
    int NF, js;
    if (F == 512)      { NF = 8; js = 1; }
    else if (F == 256) { NF = 8; js = 2; }
    else if (F == 128) { NF = 8; js = 4; }
    else if (F == 64)  { NF = 4; js = 4; }
    else               { NF = 1; js = 4; }
    int fc = F / (16 * NF);
    dim3 grid(128, fc, js);

    gemm_xw<<<dim3(128, (F + 63) / 64), dim3(128), 0, stream>>>(Xin, WT[t], H, HTt, K, F);
    gemv_srctgt<<<dim3(1024), dim3(256), 0, stream>>>(H, At, srcv, Ev16, Gv16, F);
    launch_pass2(NF, grid, (const unsigned*)bits, srcv, Ev16, Gv16, HTt, Ot, part,
                 ls0, part_ls, F, js, stream);
    if (js > 1)
      reduce_add<<<dim3((NROWS * F + 255) / 256), dim3(256), 0, stream>>>(part, part_ls, ls0, Ot,
                                                                          NROWS * F, F, js - 1);
  }
}

// Round 7
// 483.715 us; speedup vs baseline: 1.0568x; 1.0568x over previous
//
#include <hip/hip_runtime.h>
#include <hip/hip_bf16.h>
#include <hip/hip_fp16.h>

// GAE: 8 stacked GAT layers on N=4096 nodes, dims 512->256->128->64->16->64->128->256->512.
// Outputs (concat in d_out): x_bar[4096*512], h1[4096*256], h2[4096*128], h3[4096*64], h4[4096*16].
//
// Per layer:
//   H = X @ W                      (bf16 MFMA GEMM, fp32 accum; HTt fp16 j-tiled layout written
//                                   directly from the GEMM epilogue via LDS)
//   src = H @ a[:f], tgt = H @ a[f:]; Ev16 = half(exp(t-TM)*2^14), Gv16 = half(exp(.2(t-TM))*2^4)
//     with CONSTANT TM=12 (factorization exact for any upper bound TM >= max tgt)
//   pass2f: OUT[i,:] = softmax_j(lrelu(s_i+t_j) masked) @ H computed UNNORMALIZED + ones-column:
//     w~_ij = max(P_i*Ev_j, Q_i*Gv_j) in packed fp16 (P,Q from src_i in-kernel — NO pass1 kernel);
//     lsum_i = sum_j w~_ij accumulated by an extra MFMA with B = all-ones (exact row-sums of the
//     same fp16 weights fed to the product MFMAs). js==1: divide in epilogue; js>1: lsum partials
//     (ls0/part_ls) folded + divided in reduce_add.
//
// Round-7: EXACT R0 (proven 461us) + __launch_bounds__(256, 3) on pass2f ONLY.
// Evidence ladder: eff B-read BW tracks resident waves (R0 2 w/SIMD: 10.9 TB/s; R1 ~6 w/SIMD:
// 16.5 TB/s) while traffic tracks i-blocks. R0's unified footprint ~180 regs (108 arch + 72 acc)
// > 170 (=512-reg pool / 3 waves) pins 2 waves/SIMD. The ,3 bound asks the allocator to shave
// ~10 arch VGPRs (108 -> <=98) -> 3 waves/SIMD, +50% latency-hiding at IDENTICAL traffic.
// (R3's ",4" demanded <=56 arch -> catastrophic acc spill; 3-wave squeeze is mild.)
// Falsifier: FETCH/WRITE balloon => spill => revert. Numerics bitwise identical to R0.
// NO atomics, no memset -> bitwise deterministic.

#define NROWS 4096
#define TMC 12.0f

typedef __attribute__((ext_vector_type(8))) short v8s;
typedef __attribute__((ext_vector_type(8))) _Float16 v8h;
typedef __attribute__((ext_vector_type(2))) _Float16 h2v;
typedef __attribute__((ext_vector_type(4))) float v4f;

__device__ inline unsigned short f2bf(float x) {
  union { float f; unsigned u; } v; v.f = x;
  unsigned r = v.u + 0x7fffu + ((v.u >> 16) & 1u);   // RNE
  return (unsigned short)(r >> 16);
}

// ---- pack adj (int32 0/1) -> bitmask, 64 uint64 words per row ----
__global__ void pack_adj(const int* __restrict__ adj, unsigned long long* __restrict__ bits) {
  int row = blockIdx.x;
  int lane = threadIdx.x & 63, wave = threadIdx.x >> 6;
  for (int w = wave; w < 64; w += 4) {
    unsigned long long m = __ballot(adj[(size_t)row * NROWS + w * 64 + lane] > 0);
    if (lane == 0) bits[row * 64 + w] = m;
  }
}

// ---- batched W transpose: fp32 [K][F] -> bf16 [F][K], all 8 layers in one launch ----
struct WTArgs { const float* src[8]; unsigned short* dst[8]; int K[8]; int F[8]; };
__global__ void transpose_w(WTArgs A) {
  int z = blockIdx.z;
  const float* in = A.src[z];
  unsigned short* out = A.dst[z];
  int R = A.K[z], C = A.F[z];
  __shared__ unsigned short tile[32][33];
  int c0 = blockIdx.x * 32, r0 = blockIdx.y * 32;
  if (c0 >= C || r0 >= R) return;          // block-uniform: safe before barrier
#pragma unroll
  for (int dy = 0; dy < 32; dy += 8) {
    int r = r0 + threadIdx.y + dy, c = c0 + threadIdx.x;
    if (r < R && c < C) tile[threadIdx.y + dy][threadIdx.x] = f2bf(in[(size_t)r * C + c]);
  }
  __syncthreads();
#pragma unroll
  for (int dy = 0; dy < 32; dy += 8) {
    int c = c0 + threadIdx.y + dy, r = r0 + threadIdx.x;
    if (r < R && c < C) out[(size_t)c * R + r] = tile[threadIdx.x][threadIdx.y + dy];
  }
}

// ---- C[4096][Nf] = A_f32[4096][K] x B[K][Nf], B given as BT[Nf][K] bf16 ----
// 2 waves/block, 16 rows each; grid (128, ceil(Nf/64)).
// Epilogue writes HTt[j/32][f][j%32] in fp16 directly (LDS-staged).
__global__ __launch_bounds__(128) void gemm_xw(const float* __restrict__ A,
                                               const unsigned short* __restrict__ BT,
                                               float* __restrict__ C,
                                               unsigned short* __restrict__ HTt,
                                               int K, int Nf) {
  __shared__ unsigned short zone[64 * 36];         // [f_local][j_local], stride 36 vs banks
  int lane = threadIdx.x & 63, wave = threadIdx.x >> 6;
  int quad = lane >> 4, l16 = lane & 15;
  int row0 = blockIdx.x * 32 + wave * 16;
  int col0 = blockIdx.y * 64;
  int nf = Nf - col0; nf = nf > 64 ? 4 : (nf + 15) / 16;
  v4f acc[4] = {{0.f,0.f,0.f,0.f},{0.f,0.f,0.f,0.f},{0.f,0.f,0.f,0.f},{0.f,0.f,0.f,0.f}};
  for (int k0 = 0; k0 < K; k0 += 32) {
    int kk = k0 + quad * 8;
    v8s a = {0,0,0,0,0,0,0,0};
    if (kk < K) {
      float4 f0 = *(const float4*)(A + (size_t)(row0 + l16) * K + kk);
      float4 f1 = *(const float4*)(A + (size_t)(row0 + l16) * K + kk + 4);
      union { v8s s; __hip_bfloat162 h[4]; } ua;
      ua.h[0] = __float22bfloat162_rn(make_float2(f0.x, f0.y));
      ua.h[1] = __float22bfloat162_rn(make_float2(f0.z, f0.w));
      ua.h[2] = __float22bfloat162_rn(make_float2(f1.x, f1.y));
      ua.h[3] = __float22bfloat162_rn(make_float2(f1.z, f1.w));
      a = ua.s;
    }
    for (int t = 0; t < nf; t++) {
      v8s b = {0,0,0,0,0,0,0,0};
      if (kk < K) b = *(const v8s*)(BT + (size_t)(col0 + t * 16 + l16) * K + kk);
      acc[t] = __builtin_amdgcn_mfma_f32_16x16x32_bf16(a, b, acc[t], 0, 0, 0);
    }
  }
  for (int t = 0; t < nf; t++) {
#pragma unroll
    for (int r = 0; r < 4; r++) {
      float v = acc[t][r];
      C[(size_t)(row0 + quad * 4 + r) * Nf + col0 + t * 16 + l16] = v;
      union { _Float16 h; unsigned short s; } cv; cv.h = (_Float16)v;
      zone[(t * 16 + l16) * 36 + wave * 16 + quad * 4 + r] = cv.s;
    }
  }
  __syncthreads();
  unsigned* dst = (unsigned*)(HTt + (size_t)(blockIdx.x) * Nf * 32 + (size_t)col0 * 32);
  const unsigned* zsrc = (const unsigned*)zone;
  int total = nf * 256;                            // dwords (nf*16 f-rows x 32 shorts each)
  for (int idx = threadIdx.x; idx < total; idx += 128) {
    int f = idx >> 4, jp = idx & 15;
    dst[idx] = zsrc[f * 18 + jp];
  }
}

// ---- src + scaled-fp16 Ev/Gv: per-row dots of H with a[:f], a[f:] ----
__global__ void gemv_srctgt(const float* __restrict__ H, const float* __restrict__ a,
                            float* __restrict__ src, unsigned short* __restrict__ Ev16,
                            unsigned short* __restrict__ Gv16, int f) {
  int row = blockIdx.x * 4 + (threadIdx.x >> 6);
  int lane = threadIdx.x & 63;
  float s = 0.f, t = 0.f;
  for (int k = lane; k < f; k += 64) {
    float h = H[(size_t)row * f + k];
    s += h * a[k];
    t += h * a[f + k];
  }
#pragma unroll
  for (int off = 32; off; off >>= 1) { s += __shfl_down(s, off); t += __shfl_down(t, off); }
  if (lane == 0) {
    src[row] = s;
    union { _Float16 h; unsigned short u; } ce, cg;
    ce.h = (_Float16)(__expf(t - TMC) * 16384.f);  // *2^14 (exact pow2)
    cg.h = (_Float16)(__expf(0.2f * (t - TMC)) * 16.f);   // *2^4 (exact pow2)
    Ev16[row] = ce.u;
    Gv16[row] = cg.u;
  }
}

// ---- pass2f: OUT = P @ H unnormalized + MFMA ones-column lsum; packed fp16 A-build ----
// grid (128, fc, js): z=0 stores to out (+ls0), z>0 to part slab z-1 (+part_ls).
// __launch_bounds__(256, 3): target 3 waves/SIMD (arch VGPR budget ~98 = 170 - 72 acc).
template<int NF>
__global__ __launch_bounds__(256, 3) void pass2f(const unsigned* __restrict__ adjW,
                                                 const float* __restrict__ src,
                                                 const unsigned short* __restrict__ Ev16,
                                                 const unsigned short* __restrict__ Gv16,
                                                 const unsigned short* __restrict__ HTt,
                                                 float* __restrict__ out,
                                                 float* __restrict__ part,
                                                 float* __restrict__ ls0,
                                                 float* __restrict__ part_ls, int F, int js) {
  const int W = NF * 16, Wp = W + 4;               // pad col W holds lsum; rest kills conflicts
  __shared__ float zone[32 * Wp];
  int lane = threadIdx.x & 63, wave = threadIdx.x >> 6;
  int quad = lane >> 4, l16 = lane & 15;
  int i0 = blockIdx.x * 32;
  int fc0 = blockIdx.y * W;
  const size_t F32 = (size_t)F * 32;
  int jrange = NROWS / js;
  int jlen = jrange / 4;                           // multiple of 128 for js in {1,2,4}
  int jstart = blockIdx.z * jrange + wave * jlen;

  h2v Ai2[2], Bi2[2];
  const unsigned* arow[2];
#pragma unroll
  for (int ni = 0; ni < 2; ni++) {
    int i = i0 + ni * 16 + l16;
    float sp = src[i] + TMC;                       // s' = s + TM
    float m = sp > 0.f ? sp : 0.2f * sp;           // lrelu(s') >= lrelu(s+t_j) since t_j <= TM
    _Float16 ai = (_Float16)(__expf(sp - m) * 0x1p-14f);       // Ai'*Ev16 = exp(e-m) exactly
    _Float16 bi = (_Float16)(__expf(0.2f * sp - m) * 0x1p-4f); // Bi'*Gv16 = exp(.2e-m) exactly
    Ai2[ni] = (h2v){ai, ai};
    Bi2[ni] = (h2v){bi, bi};
    arow[ni] = adjW + (size_t)i * 128;             // 128 adjacency dwords per row
  }
  const v8h ones = {(_Float16)1.f, (_Float16)1.f, (_Float16)1.f, (_Float16)1.f,
                    (_Float16)1.f, (_Float16)1.f, (_Float16)1.f, (_Float16)1.f};
  v4f acc[2][NF], accl[2];
#pragma unroll
  for (int ni = 0; ni < 2; ni++) {
    accl[ni] = (v4f){0.f, 0.f, 0.f, 0.f};
#pragma unroll
    for (int t = 0; t < NF; t++) acc[ni][t] = (v4f){0.f, 0.f, 0.f, 0.f};
  }

  for (int j0 = jstart; j0 < jstart + jlen; j0 += 128) {
    uint4 aw[2];
    aw[0] = *(const uint4*)(arow[0] + (j0 >> 5));  // 4 iters of adjacency, 16B aligned
    aw[1] = *(const uint4*)(arow[1] + (j0 >> 5));
    unsigned awa[2][4] = {{aw[0].x, aw[0].y, aw[0].z, aw[0].w},
                          {aw[1].x, aw[1].y, aw[1].z, aw[1].w}};
#pragma unroll
    for (int u = 0; u < 4; u++) {
      int ju = j0 + u * 32;
      int jb = ju + quad * 8;
      union { v8s s; h2v h2[4]; } ue, ug;
      ue.s = *(const v8s*)(Ev16 + jb);
      ug.s = *(const v8s*)(Gv16 + jb);
      const unsigned short* bp =
          HTt + (size_t)(ju >> 5) * F32 + (size_t)(fc0 + l16) * 32 + quad * 8;
      union { v8s s; v8h h; } bfr[NF];
#pragma unroll
      for (int t = 0; t < NF; t++) bfr[t].s = *(const v8s*)(bp + t * 512);
#pragma unroll
      for (int ni = 0; ni < 2; ni++) {
        unsigned bb = awa[ni][u] >> (quad * 8);
        union { v8h h; unsigned u32[4]; } ua;
#pragma unroll
        for (int p = 0; p < 4; p++) {
          h2v w2 = __builtin_elementwise_max(Ai2[ni] * ue.h2[p], Bi2[ni] * ug.h2[p]);
          unsigned msk = (((bb >> (2 * p)) & 1u) ? 0x0000FFFFu : 0u)
                       | (((bb >> (2 * p + 1)) & 1u) ? 0xFFFF0000u : 0u);
          union { h2v h2; unsigned u; } tw; tw.h2 = w2;
          ua.u32[p] = tw.u & msk;
        }
#pragma unroll
        for (int t = 0; t < NF; t++)
          acc[ni][t] = __builtin_amdgcn_mfma_f32_16x16x32_f16(ua.h, bfr[t].h, acc[ni][t], 0, 0, 0);
        accl[ni] = __builtin_amdgcn_mfma_f32_16x16x32_f16(ua.h, ones, accl[ni], 0, 0, 0);
      }
    }
  }

  // deterministic combine: waves add into zone in fixed order (lsum in column W)
  for (int w = 0; w < 4; w++) {
    if (wave == w) {
#pragma unroll
      for (int ni = 0; ni < 2; ni++) {
#pragma unroll
        for (int t = 0; t < NF; t++)
#pragma unroll
          for (int r = 0; r < 4; r++) {
            int idx = (ni * 16 + quad * 4 + r) * Wp + t * 16 + l16;
            if (w == 0) zone[idx] = acc[ni][t][r];
            else        zone[idx] += acc[ni][t][r];
          }
        if (l16 == 0) {
#pragma unroll
          for (int r = 0; r < 4; r++) {
            int idx = (ni * 16 + quad * 4 + r) * Wp + W;
            if (w == 0) zone[idx] = accl[ni][r];
            else        zone[idx] += accl[ni][r];
          }
        }
      }
    }
    __syncthreads();
  }

  if (js == 1) {
    if (threadIdx.x < 32) zone[threadIdx.x * Wp + W] = 1.0f / zone[threadIdx.x * Wp + W];
    __syncthreads();
    for (int idx = threadIdx.x; idx < 32 * W; idx += 256) {
      int rrow = idx / W, ccol = idx - rrow * W;
      out[(size_t)(i0 + rrow) * F + fc0 + ccol] = zone[rrow * Wp + ccol] * zone[rrow * Wp + W];
    }
  } else {
    float* dst = (blockIdx.z == 0) ? out : part + (size_t)(blockIdx.z - 1) * NROWS * F;
    for (int idx = threadIdx.x; idx < 32 * W; idx += 256) {
      int rrow = idx / W, ccol = idx - rrow * W;
      dst[(size_t)(i0 + rrow) * F + fc0 + ccol] = zone[rrow * Wp + ccol];
    }
    if (threadIdx.x < 32) {
      float l = zone[threadIdx.x * Wp + W];
      if (blockIdx.z == 0) ls0[i0 + threadIdx.x] = l;             // fc dups write same value
      else part_ls[(size_t)(blockIdx.z - 1) * NROWS + i0 + threadIdx.x] = l;
    }
  }
}

// ---- deterministic cross-z fold + normalize: out = (out + sum slabs) / (ls0 + sum part_ls) ----
__global__ void reduce_add(const float* __restrict__ part, const float* __restrict__ part_ls,
                           const float* __restrict__ ls0, float* __restrict__ out, int n, int F,
                           int nslab) {
  int i = blockIdx.x * 256 + threadIdx.x;
  if (i < n) {
    int row = i / F;                               // F is a power of two
    float s = out[i];
    float l = ls0[row];
    for (int z = 0; z < nslab; z++) s += part[(size_t)z * n + i];
    for (int z = 0; z < nslab; z++) l += part_ls[(size_t)z * NROWS + row];
    out[i] = s / l;
  }
}

static void launch_pass2(int NF, dim3 grid, const unsigned* adjW, const float* src,
                         const unsigned short* Ev16, const unsigned short* Gv16,
                         const unsigned short* HTt, float* out, float* part, float* ls0,
                         float* part_ls, int F, int js, hipStream_t stream) {
  switch (NF) {
    case 8: pass2f<8><<<grid, 256, 0, stream>>>(adjW, src, Ev16, Gv16, HTt, out, part, ls0,
                                                part_ls, F, js); break;
    case 4: pass2f<4><<<grid, 256, 0, stream>>>(adjW, src, Ev16, Gv16, HTt, out, part, ls0,
                                                part_ls, F, js); break;
    default: pass2f<1><<<grid, 256, 0, stream>>>(adjW, src, Ev16, Gv16, HTt, out, part, ls0,
                                                 part_ls, F, js); break;
  }
}

extern "C" void kernel_launch(void* const* d_in, const int* in_sizes, int n_in,
                              void* d_out, int out_size, void* d_ws, size_t ws_size,
                              hipStream_t stream) {
  static const int fin[8]  = {512, 256, 128, 64, 16, 64, 128, 256};
  static const int fout[8] = {256, 128, 64, 16, 64, 128, 256, 512};

  const float* x = (const float*)d_in[0];
  const int* adj = (const int*)d_in[1];
  char* ws = (char*)d_ws;
  unsigned long long* bits = (unsigned long long*)(ws);                 // 2 MB
  unsigned short* WTall = (unsigned short*)(ws + (2u << 20));           // <1 MB, all layers
  float* H            = (float*)(ws + (6u << 20));                      // 8 MB max
  unsigned short* HTt = (unsigned short*)(ws + (14u << 20));            // 4 MB max (fp16)
  float* srcv    = (float*)(ws + (19u << 20));                          // 16 KB
  float* ls0     = (float*)(ws + (19u << 20) + 49152);                  // 16 KB
  float* part_ls = (float*)(ws + (19u << 20) + 65536);                  // 48 KB (3 slabs)
  unsigned short* Ev16 = (unsigned short*)(ws + (19u << 20) + 114688);  // 8 KB
  unsigned short* Gv16 = (unsigned short*)(ws + (19u << 20) + 122880);  // 8 KB
  float* o5    = (float*)(ws + (20u << 20));                            // 1 MB
  float* o6    = (float*)(ws + (21u << 20));                            // 2 MB
  float* o7    = (float*)(ws + (23u << 20));                            // 4 MB
  // partial slabs ((js-1)*N*F*4 <= 6MB) alias H: H's last reader (gemv_srctgt) runs
  // before pass2f; next layer's gemm_xw rewrites H afterwards (stream-ordered).
  float* part = H;

  float* outp = (float*)d_out;
  float* xbar = outp;
  float* h1 = outp + (size_t)NROWS * 512;
  float* h2 = h1 + (size_t)NROWS * 256;
  float* h3 = h2 + (size_t)NROWS * 128;
  float* h4 = h3 + (size_t)NROWS * 64;

  float* louts[8] = {h1, h2, h3, h4, o5, o6, o7, xbar};
  const float* lins[8] = {x, h1, h2, h3, h4, o5, o6, o7};

  unsigned short* WT[8];
  { size_t off = 0;
    for (int t = 0; t < 8; t++) { WT[t] = WTall + off; off += (size_t)fin[t] * fout[t]; } }

  pack_adj<<<dim3(4096), dim3(256), 0, stream>>>(adj, bits);

  WTArgs wa;
  for (int t = 0; t < 8; t++) {
    wa.src[t] = (const float*)d_in[2 + 2 * t];
    wa.dst[t] = WT[t];
    wa.K[t] = fin[t];
    wa.F[t] = fout[t];
  }
  transpose_w<<<dim3(16, 16, 8), dim3(32, 8), 0, stream>>>(wa);

  for (int t = 0; t < 8; t++) {
    int K = fin[t], F = fout[t];
    const float* At = (const float*)d_in[3 + 2 * t];
    const float* Xin = lins[t];
    float* Ot = louts[t];

    // R0's proven configs: minimize fc (A-build replicas) at NF=8; 512-block grids.
    int NF = F >= 128 ? 8 : (F >= 64 ? 4 : 1);
    int fc = F / (16 * NF);
    int js = (F == 512) ? 1 : (F == 256 ? 2 : 4);

    gemm_xw<<<dim3(128, (F + 63) / 64), dim3(128), 0, stream>>>(Xin, WT[t], H, HTt, K, F);
    gemv_srctgt<<<dim3(1024), dim3(256), 0, stream>>>(H, At, srcv, Ev16, Gv16, F);
    launch_pass2(NF, dim3(128, fc, js), (const unsigned*)bits, srcv, Ev16, Gv16, HTt, Ot, part,
                 ls0, part_ls, F, js, stream);
    if (js > 1)
      reduce_add<<<dim3((NROWS * F + 255) / 256), dim3(256), 0, stream>>>(part, part_ls, ls0, Ot,
                                                                          NROWS * F, F, js - 1);
  }
}

// Round 8
// 472.632 us; speedup vs baseline: 1.0815x; 1.0234x over previous
//
#include <hip/hip_runtime.h>
#include <hip/hip_bf16.h>
#include <hip/hip_fp16.h>

// GAE: 8 stacked GAT layers on N=4096 nodes, dims 512->256->128->64->16->64->128->256->512.
// Outputs (concat in d_out): x_bar[4096*512], h1[4096*256], h2[4096*128], h3[4096*64], h4[4096*16].
//
// Per layer:
//   H = X @ W                      (bf16 MFMA GEMM, fp32 accum; HTt fp16 j-tiled layout written
//                                   directly from the GEMM epilogue via LDS)
//   src = H @ a[:f], tgt = H @ a[f:]; Ev16 = half(exp(t-TM)*2^14), Gv16 = half(exp(.2(t-TM))*2^4)
//     with CONSTANT TM=12 (factorization exact for any upper bound TM >= max tgt)
//   pass2: OUT[i,:] = softmax_j(lrelu(s_i+t_j) masked) @ H computed UNNORMALIZED + ones-column
//     lsum via extra MFMA with B = all-ones; cross-z partials folded + divided in reduce_add.
//
// Round-8 (structural): R0-R7 proved pass2f is latency/L2-bound because its 4 waves read
// DISJOINT j-ranges -> each wave privately streams the whole B-panel from L2/L3 (512MB @F=512,
// ~11TB/s eff -> 47us) and no occupancy/reg/grid knob moves that product (R1 2x traffic, R3/R6/R7
// reg experiments all regressed). NEW pass2s: all 4 waves share ONE j-range, split i instead
// (wave owns 16*NI rows); the shared 64-j B-tile is staged through double-buffered LDS
// (global->reg prefetch issued BEFORE compute, ds_write after = T14 async split; one barrier
// per step). B-traffic /4, per-wave global loads /8, no zone combine (waves own rows).
// Per-row j-accumulation stays ascending 32-j MFMA chunks; cross-z folds via deterministic
// reduce_add. F in {128,256,512} use pass2s; F in {16,64} keep R0 pass2f (A-build-dominated).
// NO atomics, no memset -> deterministic.

#define NROWS 4096
#define TMC 12.0f

typedef __attribute__((ext_vector_type(8))) short v8s;
typedef __attribute__((ext_vector_type(8))) _Float16 v8h;
typedef __attribute__((ext_vector_type(2))) _Float16 h2v;
typedef __attribute__((ext_vector_type(4))) float v4f;

__device__ inline unsigned short f2bf(float x) {
  union { float f; unsigned u; } v; v.f = x;
  unsigned r = v.u + 0x7fffu + ((v.u >> 16) & 1u);   // RNE
  return (unsigned short)(r >> 16);
}

// ---- pack adj (int32 0/1) -> bitmask, 64 uint64 words per row ----
__global__ void pack_adj(const int* __restrict__ adj, unsigned long long* __restrict__ bits) {
  int row = blockIdx.x;
  int lane = threadIdx.x & 63, wave = threadIdx.x >> 6;
  for (int w = wave; w < 64; w += 4) {
    unsigned long long m = __ballot(adj[(size_t)row * NROWS + w * 64 + lane] > 0);
    if (lane == 0) bits[row * 64 + w] = m;
  }
}

// ---- batched W transpose: fp32 [K][F] -> bf16 [F][K], all 8 layers in one launch ----
struct WTArgs { const float* src[8]; unsigned short* dst[8]; int K[8]; int F[8]; };
__global__ void transpose_w(WTArgs A) {
  int z = blockIdx.z;
  const float* in = A.src[z];
  unsigned short* out = A.dst[z];
  int R = A.K[z], C = A.F[z];
  __shared__ unsigned short tile[32][33];
  int c0 = blockIdx.x * 32, r0 = blockIdx.y * 32;
  if (c0 >= C || r0 >= R) return;          // block-uniform: safe before barrier
#pragma unroll
  for (int dy = 0; dy < 32; dy += 8) {
    int r = r0 + threadIdx.y + dy, c = c0 + threadIdx.x;
    if (r < R && c < C) tile[threadIdx.y + dy][threadIdx.x] = f2bf(in[(size_t)r * C + c]);
  }
  __syncthreads();
#pragma unroll
  for (int dy = 0; dy < 32; dy += 8) {
    int c = c0 + threadIdx.y + dy, r = r0 + threadIdx.x;
    if (r < R && c < C) out[(size_t)c * R + r] = tile[threadIdx.x][threadIdx.y + dy];
  }
}

// ---- C[4096][Nf] = A_f32[4096][K] x B[K][Nf], B given as BT[Nf][K] bf16 ----
__global__ __launch_bounds__(128) void gemm_xw(const float* __restrict__ A,
                                               const unsigned short* __restrict__ BT,
                                               float* __restrict__ C,
                                               unsigned short* __restrict__ HTt,
                                               int K, int Nf) {
  __shared__ unsigned short zone[64 * 36];         // [f_local][j_local], stride 36 vs banks
  int lane = threadIdx.x & 63, wave = threadIdx.x >> 6;
  int quad = lane >> 4, l16 = lane & 15;
  int row0 = blockIdx.x * 32 + wave * 16;
  int col0 = blockIdx.y * 64;
  int nf = Nf - col0; nf = nf > 64 ? 4 : (nf + 15) / 16;
  v4f acc[4] = {{0.f,0.f,0.f,0.f},{0.f,0.f,0.f,0.f},{0.f,0.f,0.f,0.f},{0.f,0.f,0.f,0.f}};
  for (int k0 = 0; k0 < K; k0 += 32) {
    int kk = k0 + quad * 8;
    v8s a = {0,0,0,0,0,0,0,0};
    if (kk < K) {
      float4 f0 = *(const float4*)(A + (size_t)(row0 + l16) * K + kk);
      float4 f1 = *(const float4*)(A + (size_t)(row0 + l16) * K + kk + 4);
      union { v8s s; __hip_bfloat162 h[4]; } ua;
      ua.h[0] = __float22bfloat162_rn(make_float2(f0.x, f0.y));
      ua.h[1] = __float22bfloat162_rn(make_float2(f0.z, f0.w));
      ua.h[2] = __float22bfloat162_rn(make_float2(f1.x, f1.y));
      ua.h[3] = __float22bfloat162_rn(make_float2(f1.z, f1.w));
      a = ua.s;
    }
    for (int t = 0; t < nf; t++) {
      v8s b = {0,0,0,0,0,0,0,0};
      if (kk < K) b = *(const v8s*)(BT + (size_t)(col0 + t * 16 + l16) * K + kk);
      acc[t] = __builtin_amdgcn_mfma_f32_16x16x32_bf16(a, b, acc[t], 0, 0, 0);
    }
  }
  for (int t = 0; t < nf; t++) {
#pragma unroll
    for (int r = 0; r < 4; r++) {
      float v = acc[t][r];
      C[(size_t)(row0 + quad * 4 + r) * Nf + col0 + t * 16 + l16] = v;
      union { _Float16 h; unsigned short s; } cv; cv.h = (_Float16)v;
      zone[(t * 16 + l16) * 36 + wave * 16 + quad * 4 + r] = cv.s;
    }
  }
  __syncthreads();
  unsigned* dst = (unsigned*)(HTt + (size_t)(blockIdx.x) * Nf * 32 + (size_t)col0 * 32);
  const unsigned* zsrc = (const unsigned*)zone;
  int total = nf * 256;                            // dwords (nf*16 f-rows x 32 shorts each)
  for (int idx = threadIdx.x; idx < total; idx += 128) {
    int f = idx >> 4, jp = idx & 15;
    dst[idx] = zsrc[f * 18 + jp];
  }
}

// ---- src + scaled-fp16 Ev/Gv: per-row dots of H with a[:f], a[f:] ----
__global__ void gemv_srctgt(const float* __restrict__ H, const float* __restrict__ a,
                            float* __restrict__ src, unsigned short* __restrict__ Ev16,
                            unsigned short* __restrict__ Gv16, int f) {
  int row = blockIdx.x * 4 + (threadIdx.x >> 6);
  int lane = threadIdx.x & 63;
  float s = 0.f, t = 0.f;
  for (int k = lane; k < f; k += 64) {
    float h = H[(size_t)row * f + k];
    s += h * a[k];
    t += h * a[f + k];
  }
#pragma unroll
  for (int off = 32; off; off >>= 1) { s += __shfl_down(s, off); t += __shfl_down(t, off); }
  if (lane == 0) {
    src[row] = s;
    union { _Float16 h; unsigned short u; } ce, cg;
    ce.h = (_Float16)(__expf(t - TMC) * 16384.f);  // *2^14 (exact pow2)
    cg.h = (_Float16)(__expf(0.2f * (t - TMC)) * 16.f);   // *2^4 (exact pow2)
    Ev16[row] = ce.u;
    Gv16[row] = cg.u;
  }
}

// ---- pass2s: LDS-shared-B pass2. 4 waves share one j-range, split i. ----
// Block: 64*NI i-rows (wave owns 16*NI), W=16*NF f-cols, j-chunk = NROWS/js.
// Per 64-j step: 256 threads stage [W][64] HTt tile into double-buffered LDS (rows padded
// to 72 shorts = 144B, 16B-aligned b128 ops, 2-way max bank alias); prefetch (global->reg)
// issued before compute so HBM/L2 latency hides under MFMA+VALU; ds_write after; 1 barrier.
template<int NF, int NI>
__global__ __launch_bounds__(256) void pass2s(const unsigned* __restrict__ adjW,
                                              const float* __restrict__ src,
                                              const unsigned short* __restrict__ Ev16,
                                              const unsigned short* __restrict__ Gv16,
                                              const unsigned short* __restrict__ HTt,
                                              float* __restrict__ out,
                                              float* __restrict__ part,
                                              float* __restrict__ ls0,
                                              float* __restrict__ part_ls, int F, int js) {
  constexpr int W = NF * 16;
  constexpr int LROW = 72;                          // 64 j + 8 pad shorts (144B rows)
  constexpr int SH = (W == 128) ? 9 : (W == 64) ? 8 : 7;   // log2(W*4)
  constexpr int NCH = (W * 8) / 256;                // 16B chunks per thread per tile
  __shared__ unsigned short bs[2][W * LROW];

  int lane = threadIdx.x & 63, wave = threadIdx.x >> 6;
  int quad = lane >> 4, l16 = lane & 15;
  int i0 = blockIdx.x * (64 * NI) + wave * (16 * NI);
  int fc0 = blockIdx.y * W;
  const size_t F32 = (size_t)F * 32;
  int jrange = NROWS / js;
  int nsteps = jrange / 64;
  int jstart = blockIdx.z * jrange;

  h2v Ai2[NI], Bi2[NI];
  const unsigned* arow[NI];
#pragma unroll
  for (int ni = 0; ni < NI; ni++) {
    int i = i0 + ni * 16 + l16;
    float sp = src[i] + TMC;
    float m = sp > 0.f ? sp : 0.2f * sp;
    _Float16 ai = (_Float16)(__expf(sp - m) * 0x1p-14f);
    _Float16 bi = (_Float16)(__expf(0.2f * sp - m) * 0x1p-4f);
    Ai2[ni] = (h2v){ai, ai};
    Bi2[ni] = (h2v){bi, bi};
    arow[ni] = adjW + (size_t)i * 128;
  }
  const v8h ones = {(_Float16)1.f, (_Float16)1.f, (_Float16)1.f, (_Float16)1.f,
                    (_Float16)1.f, (_Float16)1.f, (_Float16)1.f, (_Float16)1.f};
  v4f acc[NI][NF], accl[NI];
#pragma unroll
  for (int ni = 0; ni < NI; ni++) {
    accl[ni] = (v4f){0.f, 0.f, 0.f, 0.f};
#pragma unroll
    for (int t = 0; t < NF; t++) acc[ni][t] = (v4f){0.f, 0.f, 0.f, 0.f};
  }

  // staging map: chunk g = tid + 256k covers (jt_h = g>>SH, f = (g&(W*4-1))>>2, c = g&3)
  int srcRel[NCH], dstOff[NCH];
#pragma unroll
  for (int k = 0; k < NCH; k++) {
    int g = threadIdx.x + 256 * k;
    int jt_h = g >> SH;
    int rem = g & ((W * 4) - 1);
    int f = rem >> 2, c = rem & 3;
    srcRel[k] = jt_h * (int)F32 + f * 32 + c * 8;   // shorts
    dstOff[k] = f * LROW + jt_h * 32 + c * 8;       // shorts
  }
  const unsigned short* sbase = HTt + ((size_t)(jstart >> 5)) * F32 + (size_t)fc0 * 32;

  v8s sreg[NCH];
  v8s uePf[2], ugPf[2];
  uint2 awPf[NI];

  // prologue: stage step 0 + its metadata
#pragma unroll
  for (int k = 0; k < NCH; k++) sreg[k] = *(const v8s*)(sbase + srcRel[k]);
#pragma unroll
  for (int h = 0; h < 2; h++) {
    uePf[h] = *(const v8s*)(Ev16 + jstart + h * 32 + quad * 8);
    ugPf[h] = *(const v8s*)(Gv16 + jstart + h * 32 + quad * 8);
  }
#pragma unroll
  for (int ni = 0; ni < NI; ni++) awPf[ni] = *(const uint2*)(arow[ni] + (jstart >> 5));
#pragma unroll
  for (int k = 0; k < NCH; k++) *(v8s*)(&bs[0][dstOff[k]]) = sreg[k];
  __syncthreads();

  int cur = 0;
  for (int s = 0; s < nsteps; s++) {
    int j0 = jstart + s * 64;
    v8s ueL0 = uePf[0], ueL1 = uePf[1], ugL0 = ugPf[0], ugL1 = ugPf[1];
    uint2 awL[NI];
#pragma unroll
    for (int ni = 0; ni < NI; ni++) awL[ni] = awPf[ni];

    if (s + 1 < nsteps) {                 // issue next-step loads (hidden under compute)
      const unsigned short* sb1 = sbase + (size_t)(s + 1) * 2 * F32;
#pragma unroll
      for (int k = 0; k < NCH; k++) sreg[k] = *(const v8s*)(sb1 + srcRel[k]);
      int j1 = j0 + 64;
#pragma unroll
      for (int h = 0; h < 2; h++) {
        uePf[h] = *(const v8s*)(Ev16 + j1 + h * 32 + quad * 8);
        ugPf[h] = *(const v8s*)(Gv16 + j1 + h * 32 + quad * 8);
      }
#pragma unroll
      for (int ni = 0; ni < NI; ni++) awPf[ni] = *(const uint2*)(arow[ni] + (j1 >> 5));
    }

#pragma unroll
    for (int half = 0; half < 2; half++) {
      union { v8s s; h2v h2[4]; } ue, ug;
      ue.s = half ? ueL1 : ueL0;
      ug.s = half ? ugL1 : ugL0;
      const unsigned short* lb = &bs[cur][half * 32 + quad * 8];
      union { v8s s; v8h h; } bfr[NF];
#pragma unroll
      for (int t = 0; t < NF; t++) bfr[t].s = *(const v8s*)(lb + (l16 + t * 16) * LROW);
#pragma unroll
      for (int ni = 0; ni < NI; ni++) {
        unsigned bb = (half ? awL[ni].y : awL[ni].x) >> (quad * 8);
        union { v8h h; unsigned u32[4]; } ua;
#pragma unroll
        for (int p = 0; p < 4; p++) {
          h2v w2 = __builtin_elementwise_max(Ai2[ni] * ue.h2[p], Bi2[ni] * ug.h2[p]);
          unsigned msk = (((bb >> (2 * p)) & 1u) ? 0x0000FFFFu : 0u)
                       | (((bb >> (2 * p + 1)) & 1u) ? 0xFFFF0000u : 0u);
          union { h2v h2; unsigned u; } tw; tw.h2 = w2;
          ua.u32[p] = tw.u & msk;
        }
#pragma unroll
        for (int t = 0; t < NF; t++)
          acc[ni][t] = __builtin_amdgcn_mfma_f32_16x16x32_f16(ua.h, bfr[t].h, acc[ni][t], 0, 0, 0);
        accl[ni] = __builtin_amdgcn_mfma_f32_16x16x32_f16(ua.h, ones, accl[ni], 0, 0, 0);
      }
    }

    if (s + 1 < nsteps) {
#pragma unroll
      for (int k = 0; k < NCH; k++) *(v8s*)(&bs[cur ^ 1][dstOff[k]]) = sreg[k];
    }
    __syncthreads();
    cur ^= 1;
  }

  // epilogue: waves own their rows exclusively -> direct store, no cross-wave combine.
  float* dst = (blockIdx.z == 0) ? out : part + (size_t)(blockIdx.z - 1) * NROWS * F;
#pragma unroll
  for (int ni = 0; ni < NI; ni++)
#pragma unroll
    for (int t = 0; t < NF; t++)
#pragma unroll
      for (int r = 0; r < 4; r++)
        dst[(size_t)(i0 + ni * 16 + quad * 4 + r) * F + fc0 + t * 16 + l16] = acc[ni][t][r];
  if (l16 == 0) {                                   // lsum: col-independent, lanes 0/16/32/48
    float* ldst = (blockIdx.z == 0) ? ls0 : part_ls + (size_t)(blockIdx.z - 1) * NROWS;
#pragma unroll
    for (int ni = 0; ni < NI; ni++)
#pragma unroll
      for (int r = 0; r < 4; r++)
        ldst[i0 + ni * 16 + quad * 4 + r] = accl[ni][r];   // fc dups write same value
  }
}

// ---- pass2f (R0 path, kept for F=64/16): 4 waves split j, zone combine ----
template<int NF>
__global__ __launch_bounds__(256) void pass2f(const unsigned* __restrict__ adjW,
                                              const float* __restrict__ src,
                                              const unsigned short* __restrict__ Ev16,
                                              const unsigned short* __restrict__ Gv16,
                                              const unsigned short* __restrict__ HTt,
                                              float* __restrict__ out,
                                              float* __restrict__ part,
                                              float* __restrict__ ls0,
                                              float* __restrict__ part_ls, int F, int js) {
  const int W = NF * 16, Wp = W + 4;
  __shared__ float zone[32 * Wp];
  int lane = threadIdx.x & 63, wave = threadIdx.x >> 6;
  int quad = lane >> 4, l16 = lane & 15;
  int i0 = blockIdx.x * 32;
  int fc0 = blockIdx.y * W;
  const size_t F32 = (size_t)F * 32;
  int jrange = NROWS / js;
  int jlen = jrange / 4;
  int jstart = blockIdx.z * jrange + wave * jlen;

  h2v Ai2[2], Bi2[2];
  const unsigned* arow[2];
#pragma unroll
  for (int ni = 0; ni < 2; ni++) {
    int i = i0 + ni * 16 + l16;
    float sp = src[i] + TMC;
    float m = sp > 0.f ? sp : 0.2f * sp;
    _Float16 ai = (_Float16)(__expf(sp - m) * 0x1p-14f);
    _Float16 bi = (_Float16)(__expf(0.2f * sp - m) * 0x1p-4f);
    Ai2[ni] = (h2v){ai, ai};
    Bi2[ni] = (h2v){bi, bi};
    arow[ni] = adjW + (size_t)i * 128;
  }
  const v8h ones = {(_Float16)1.f, (_Float16)1.f, (_Float16)1.f, (_Float16)1.f,
                    (_Float16)1.f, (_Float16)1.f, (_Float16)1.f, (_Float16)1.f};
  v4f acc[2][NF], accl[2];
#pragma unroll
  for (int ni = 0; ni < 2; ni++) {
    accl[ni] = (v4f){0.f, 0.f, 0.f, 0.f};
#pragma unroll
    for (int t = 0; t < NF; t++) acc[ni][t] = (v4f){0.f, 0.f, 0.f, 0.f};
  }

  for (int j0 = jstart; j0 < jstart + jlen; j0 += 128) {
    uint4 aw[2];
    aw[0] = *(const uint4*)(arow[0] + (j0 >> 5));
    aw[1] = *(const uint4*)(arow[1] + (j0 >> 5));
    unsigned awa[2][4] = {{aw[0].x, aw[0].y, aw[0].z, aw[0].w},
                          {aw[1].x, aw[1].y, aw[1].z, aw[1].w}};
#pragma unroll
    for (int u = 0; u < 4; u++) {
      int ju = j0 + u * 32;
      int jb = ju + quad * 8;
      union { v8s s; h2v h2[4]; } ue, ug;
      ue.s = *(const v8s*)(Ev16 + jb);
      ug.s = *(const v8s*)(Gv16 + jb);
      const unsigned short* bp =
          HTt + (size_t)(ju >> 5) * F32 + (size_t)(fc0 + l16) * 32 + quad * 8;
      union { v8s s; v8h h; } bfr[NF];
#pragma unroll
      for (int t = 0; t < NF; t++) bfr[t].s = *(const v8s*)(bp + t * 512);
#pragma unroll
      for (int ni = 0; ni < 2; ni++) {
        unsigned bb = awa[ni][u] >> (quad * 8);
        union { v8h h; unsigned u32[4]; } ua;
#pragma unroll
        for (int p = 0; p < 4; p++) {
          h2v w2 = __builtin_elementwise_max(Ai2[ni] * ue.h2[p], Bi2[ni] * ug.h2[p]);
          unsigned msk = (((bb >> (2 * p)) & 1u) ? 0x0000FFFFu : 0u)
                       | (((bb >> (2 * p + 1)) & 1u) ? 0xFFFF0000u : 0u);
          union { h2v h2; unsigned u; } tw; tw.h2 = w2;
          ua.u32[p] = tw.u & msk;
        }
#pragma unroll
        for (int t = 0; t < NF; t++)
          acc[ni][t] = __builtin_amdgcn_mfma_f32_16x16x32_f16(ua.h, bfr[t].h, acc[ni][t], 0, 0, 0);
        accl[ni] = __builtin_amdgcn_mfma_f32_16x16x32_f16(ua.h, ones, accl[ni], 0, 0, 0);
      }
    }
  }

  for (int w = 0; w < 4; w++) {
    if (wave == w) {
#pragma unroll
      for (int ni = 0; ni < 2; ni++) {
#pragma unroll
        for (int t = 0; t < NF; t++)
#pragma unroll
          for (int r = 0; r < 4; r++) {
            int idx = (ni * 16 + quad * 4 + r) * Wp + t * 16 + l16;
            if (w == 0) zone[idx] = acc[ni][t][r];
            else        zone[idx] += acc[ni][t][r];
          }
        if (l16 == 0) {
#pragma unroll
          for (int r = 0; r < 4; r++) {
            int idx = (ni * 16 + quad * 4 + r) * Wp + W;
            if (w == 0) zone[idx] = accl[ni][r];
            else        zone[idx] += accl[ni][r];
          }
        }
      }
    }
    __syncthreads();
  }

  if (js == 1) {
    if (threadIdx.x < 32) zone[threadIdx.x * Wp + W] = 1.0f / zone[threadIdx.x * Wp + W];
    __syncthreads();
    for (int idx = threadIdx.x; idx < 32 * W; idx += 256) {
      int rrow = idx / W, ccol = idx - rrow * W;
      out[(size_t)(i0 + rrow) * F + fc0 + ccol] = zone[rrow * Wp + ccol] * zone[rrow * Wp + W];
    }
  } else {
    float* dst = (blockIdx.z == 0) ? out : part + (size_t)(blockIdx.z - 1) * NROWS * F;
    for (int idx = threadIdx.x; idx < 32 * W; idx += 256) {
      int rrow = idx / W, ccol = idx - rrow * W;
      dst[(size_t)(i0 + rrow) * F + fc0 + ccol] = zone[rrow * Wp + ccol];
    }
    if (threadIdx.x < 32) {
      float l = zone[threadIdx.x * Wp + W];
      if (blockIdx.z == 0) ls0[i0 + threadIdx.x] = l;
      else part_ls[(size_t)(blockIdx.z - 1) * NROWS + i0 + threadIdx.x] = l;
    }
  }
}

// ---- deterministic cross-z fold + normalize: out = (out + sum slabs) / (ls0 + sum part_ls) ----
__global__ void reduce_add(const float* __restrict__ part, const float* __restrict__ part_ls,
                           const float* __restrict__ ls0, float* __restrict__ out, int n, int F,
                           int nslab) {
  int i = blockIdx.x * 256 + threadIdx.x;
  if (i < n) {
    int row = i / F;                               // F is a power of two
    float s = out[i];
    float l = ls0[row];
    for (int z = 0; z < nslab; z++) s += part[(size_t)z * n + i];
    for (int z = 0; z < nslab; z++) l += part_ls[(size_t)z * NROWS + row];
    out[i] = s / l;
  }
}

extern "C" void kernel_launch(void* const* d_in, const int* in_sizes, int n_in,
                              void* d_out, int out_size, void* d_ws, size_t ws_size,
                              hipStream_t stream) {
  static const int fin[8]  = {512, 256, 128, 64, 16, 64, 128, 256};
  static const int fout[8] = {256, 128, 64, 16, 64, 128, 256, 512};

  const float* x = (const float*)d_in[0];
  const int* adj = (const int*)d_in[1];
  char* ws = (char*)d_ws;
  unsigned long long* bits = (unsigned long long*)(ws);                 // 2 MB
  unsigned short* WTall = (unsigned short*)(ws + (2u << 20));           // <1 MB, all layers
  float* H            = (float*)(ws + (6u << 20));                      // 8 MB max
  unsigned short* HTt = (unsigned short*)(ws + (14u << 20));            // 4 MB max (fp16)
  float* srcv    = (float*)(ws + (19u << 20));                          // 16 KB
  float* ls0     = (float*)(ws + (19u << 20) + 49152);                  // 16 KB
  float* part_ls = (float*)(ws + (19u << 20) + 65536);                  // 48 KB (3 slabs)
  unsigned short* Ev16 = (unsigned short*)(ws + (19u << 20) + 114688);  // 8 KB
  unsigned short* Gv16 = (unsigned short*)(ws + (19u << 20) + 122880);  // 8 KB
  float* o5    = (float*)(ws + (20u << 20));                            // 1 MB
  float* o6    = (float*)(ws + (21u << 20));                            // 2 MB
  float* o7    = (float*)(ws + (23u << 20));                            // 4 MB
  // partial slabs ((js-1)*N*F*4 <= 8MB) alias H: H's last reader (gemv_srctgt) runs
  // before pass2; next layer's gemm_xw rewrites H afterwards (stream-ordered).
  float* part = H;

  float* outp = (float*)d_out;
  float* xbar = outp;
  float* h1 = outp + (size_t)NROWS * 512;
  float* h2 = h1 + (size_t)NROWS * 256;
  float* h3 = h2 + (size_t)NROWS * 128;
  float* h4 = h3 + (size_t)NROWS * 64;

  float* louts[8] = {h1, h2, h3, h4, o5, o6, o7, xbar};
  const float* lins[8] = {x, h1, h2, h3, h4, o5, o6, o7};

  unsigned short* WT[8];
  { size_t off = 0;
    for (int t = 0; t < 8; t++) { WT[t] = WTall + off; off += (size_t)fin[t] * fout[t]; } }

  pack_adj<<<dim3(4096), dim3(256), 0, stream>>>(adj, bits);

  WTArgs wa;
  for (int t = 0; t < 8; t++) {
    wa.src[t] = (const float*)d_in[2 + 2 * t];
    wa.dst[t] = WT[t];
    wa.K[t] = fin[t];
    wa.F[t] = fout[t];
  }
  transpose_w<<<dim3(16, 16, 8), dim3(32, 8), 0, stream>>>(wa);

  for (int t = 0; t < 8; t++) {
    int K = fin[t], F = fout[t];
    const float* At = (const float*)d_in[3 + 2 * t];
    const float* Xin = lins[t];
    float* Ot = louts[t];

    gemm_xw<<<dim3(128, (F + 63) / 64), dim3(128), 0, stream>>>(Xin, WT[t], H, HTt, K, F);
    gemv_srctgt<<<dim3(1024), dim3(256), 0, stream>>>(H, At, srcv, Ev16, Gv16, F);

    const unsigned* adjW = (const unsigned*)bits;
    int js;
    if (F == 512) {
      js = 2;    // slab 8MB = H alias exactly
      pass2s<8, 2><<<dim3(32, 4, js), 256, 0, stream>>>(adjW, srcv, Ev16, Gv16, HTt, Ot, part,
                                                        ls0, part_ls, F, js);
    } else if (F == 256) {
      js = 2;    // slab 4MB
      pass2s<8, 1><<<dim3(64, 2, js), 256, 0, stream>>>(adjW, srcv, Ev16, Gv16, HTt, Ot, part,
                                                        ls0, part_ls, F, js);
    } else if (F == 128) {
      js = 4;    // slabs 3x2MB
      pass2s<8, 1><<<dim3(64, 1, js), 256, 0, stream>>>(adjW, srcv, Ev16, Gv16, HTt, Ot, part,
                                                        ls0, part_ls, F, js);
    } else if (F == 64) {
      js = 4;    // R0 path
      pass2f<4><<<dim3(128, 1, js), 256, 0, stream>>>(adjW, srcv, Ev16, Gv16, HTt, Ot, part,
                                                      ls0, part_ls, F, js);
    } else {
      js = 4;    // R0 path
      pass2f<1><<<dim3(128, 1, js), 256, 0, stream>>>(adjW, srcv, Ev16, Gv16, HTt, Ot, part,
                                                      ls0, part_ls, F, js);
    }
    if (js > 1)
      reduce_add<<<dim3((NROWS * F + 255) / 256), dim3(256), 0, stream>>>(part, part_ls, ls0, Ot,
                                                                          NROWS * F, F, js - 1);
  }
}